// Round 6
// baseline (450.577 us; speedup 1.0000x reference)
//
#include <hip/hip_runtime.h>
#include <math.h>

#define BATCH 2
#define LSEQ  2048
#define EMB   2048
#define NH    16
#define HD    128

typedef __attribute__((ext_vector_type(8))) short bf16x8;
typedef __attribute__((ext_vector_type(8))) unsigned short u16x8;
typedef __attribute__((ext_vector_type(4))) float f32x4;

static __device__ __forceinline__ unsigned short f2bf(float f) {
    unsigned u = __float_as_uint(f);
    u += 0x7fffu + ((u >> 16) & 1u);
    return (unsigned short)(u >> 16);
}

// async global->LDS, 16 bytes per lane; LDS dest must be wave-uniform base + lane*16
static __device__ __forceinline__ void load_lds16(const void* g, void* l) {
    __builtin_amdgcn_global_load_lds(
        (const __attribute__((address_space(1))) void*)g,
        (__attribute__((address_space(3))) void*)l, 16, 0, 0);
}

// ---------------------------------------------------------------------------
// cast fp32 -> bf16 for x, w_attn, w_proj
// ---------------------------------------------------------------------------
#define N1 (BATCH * LSEQ * EMB)      // 8388608  (x)
#define N2 (3 * EMB * EMB)           // 12582912 (w_attn)
#define N3 (EMB * EMB)               // 4194304  (w_proj)

__global__ __launch_bounds__(256) void cast_bf16_kernel(
    const float* __restrict__ x, const float* __restrict__ wa,
    const float* __restrict__ wp,
    unsigned short* __restrict__ xb, unsigned short* __restrict__ wab,
    unsigned short* __restrict__ wpb)
{
    size_t i4 = ((size_t)blockIdx.x * 256 + threadIdx.x) * 4;
    const float* src;
    unsigned short* dst;
    size_t off;
    if (i4 < (size_t)N1) { src = x; dst = xb; off = i4; }
    else if (i4 < (size_t)N1 + N2) { src = wa; dst = wab; off = i4 - N1; }
    else { src = wp; dst = wpb; off = i4 - N1 - N2; }
    float4 f = *(const float4*)(src + off);
    ushort4 u;
    u.x = f2bf(f.x); u.y = f2bf(f.y); u.z = f2bf(f.z); u.w = f2bf(f.w);
    *(ushort4*)(dst + off) = u;
}

// ---------------------------------------------------------------------------
// MFMA bf16 GEMM, tail-free tiling + phase-interleaved double-buffer pipeline.
// Tile: (MI*32) x (NI*64), 512 threads = 8 waves (2M x 4N); per-wave MI*16 x
// NI*16 output. BK=64. Grid sized so nwg is an exact multiple of 256 CUs
// (QKV: MI=4,NI=4 -> 128x256, grid 768 = 3 exact rounds; proj: MI=8,NI=2 ->
// 256x128, grid 256 = 1 exact round) -- the round-5 384-block grid wasted 25%
// of the machine on tail quantization (687 TF observed = 916 TF * 0.75).
// Per K-tile t (reads buf rd=t&1): P = MI/2 phases, phase p = {
//   [p==0: issue FULL stage of tile t+1 into rd^1 -- max latency cover]
//   ds_read A-frag pair (+all B-frags at p==0) ; s_barrier ;
//   s_waitcnt lgkmcnt(0) ; setprio(1) ; 2*NI*2 MFMA ; setprio(0) ;
//   [p==P-1: s_waitcnt vmcnt(0) -- only tile t+1's loads outstanding, issued
//    a full tile of compute earlier] ; s_barrier }
// Hazards: stage writes rd^1 only after the t-1 final barrier (each wave's
// lgkmcnt(0) already drained its rd^1 reads before that barrier); barriers
// branch-free / count-uniform; asm waitcnts carry "memory".
// LDS chunk layout XOR-swizzled (slot row*8+c' holds chunk c'^(row&7)); reads
// swizzle identically -> measured 0 bank conflicts.
// XCD-aware bijective block swizzle (nwg % 8 == 0 at all call sites).
// mode 0: C fp32 row-major [M,N]
// mode 1: q/k scattered bf16 into [B,H,L,HD] WITH RoPE fused;
//         v scattered bf16 TRANSPOSED into [B,H,HD,L] (packed ushort4 along L)
// ---------------------------------------------------------------------------
template<int MI, int NI>   // per-wave M/N fragment counts
__global__ __launch_bounds__(512, 2) void gemm_bt_bf16(
    const unsigned short* __restrict__ A, const unsigned short* __restrict__ B,
    const float* __restrict__ rope,
    float* __restrict__ C,
    unsigned short* __restrict__ qo, unsigned short* __restrict__ ko,
    unsigned short* __restrict__ vo,
    int M, int N, int K, int mode)
{
    constexpr int BM = MI * 32;
    constexpr int BN = NI * 64;
    __shared__ __align__(16) unsigned short As[2][BM * 64];
    __shared__ __align__(16) unsigned short Bs[2][BN * 64];

    const int tid = threadIdx.x;
    const int lane = tid & 63;
    const int w = tid >> 6;      // 0..7
    const int m = lane & 15;
    const int g = lane >> 4;
    const int wr = w >> 2;       // 0..1 : M half (MI*16 rows each)
    const int wc = w & 3;        // 0..3 : N quadrant (NI*16 cols each)
    const int sw = m & 7;        // read-side swizzle key (frag rows are 16-aligned + m)

    // XCD-aware swizzle: blocks lin%8==r land on XCD r; each XCD gets a
    // contiguous tile range. nwg divisible by 8 (768 / 256).
    const int nwgx = gridDim.x;
    const int lin = blockIdx.y * nwgx + blockIdx.x;
    const int cpx = (nwgx * gridDim.y) >> 3;
    const int swz = (lin & 7) * cpx + (lin >> 3);
    const int bm = (swz / nwgx) * BM;
    const int bn = (swz % nwgx) * BN;

    // stage the whole next K-tile (A: BM x 64, B: BN x 64) into buffer `buf`.
    // loads/thread = MI/2 (A) + NI (B).
    auto stage = [&](int buf, int k0) {
#pragma unroll
        for (int i = 0; i < MI / 2; i++) {
            const int idx = i * 512 + tid;          // chunk slot 0..BM*8-1
            const int row = idx >> 3;               // 0..BM-1
            const int c = (idx & 7) ^ (row & 7);    // swizzled source chunk
            load_lds16(A + (size_t)(bm + row) * K + k0 + c * 8, &As[buf][idx * 8]);
        }
#pragma unroll
        for (int i = 0; i < NI; i++) {
            const int idx = i * 512 + tid;          // chunk slot 0..BN*8-1
            const int row = idx >> 3;               // 0..BN-1
            const int c = (idx & 7) ^ (row & 7);
            load_lds16(B + (size_t)(bn + row) * K + k0 + c * 8, &Bs[buf][idx * 8]);
        }
    };

    f32x4 acc[MI][NI];
#pragma unroll
    for (int mi = 0; mi < MI; mi++)
#pragma unroll
        for (int ni = 0; ni < NI; ni++) acc[mi][ni] = (f32x4){0.f, 0.f, 0.f, 0.f};

    const int nt = K >> 6;   // K / 64
    constexpr int P = MI / 2;

    // prologue: stage tile 0, drain, publish
    stage(0, 0);
    asm volatile("s_waitcnt vmcnt(0)" ::: "memory");
    __builtin_amdgcn_s_barrier();

    for (int t = 0; t < nt; t++) {
        const int rd = t & 1;
        const unsigned short* Ac = As[rd];
        const unsigned short* Bc = Bs[rd];
        bf16x8 bfv[NI][2];

#pragma unroll
        for (int p = 0; p < P; p++) {
            // issue the entire next-tile stage first -> a full tile of compute
            // covers its latency before the boundary vmcnt(0)
            if (p == 0 && t + 1 < nt) stage(rd ^ 1, (t + 1) * 64);

            // ds_read this phase's A-fragment pair
            bf16x8 af[2][2];
#pragma unroll
            for (int mi2 = 0; mi2 < 2; mi2++) {
                const int row = wr * (MI * 16) + (p * 2 + mi2) * 16 + m;
#pragma unroll
                for (int kc = 0; kc < 2; kc++)
                    af[mi2][kc] = *(const bf16x8*)&Ac[(row * 8 + ((kc * 4 + g) ^ sw)) * 8];
            }
            if (p == 0) {
                // all B-frags for this K-tile
#pragma unroll
                for (int ni = 0; ni < NI; ni++) {
                    const int row = wc * (NI * 16) + ni * 16 + m;
#pragma unroll
                    for (int kc = 0; kc < 2; kc++)
                        bfv[ni][kc] = *(const bf16x8*)&Bc[(row * 8 + ((kc * 4 + g) ^ sw)) * 8];
                }
            }

            __builtin_amdgcn_s_barrier();
            asm volatile("s_waitcnt lgkmcnt(0)" ::: "memory");
            __builtin_amdgcn_s_setprio(1);
#pragma unroll
            for (int mi2 = 0; mi2 < 2; mi2++)
#pragma unroll
                for (int ni = 0; ni < NI; ni++)
#pragma unroll
                    for (int kc = 0; kc < 2; kc++)
                        acc[p * 2 + mi2][ni] = __builtin_amdgcn_mfma_f32_16x16x32_bf16(
                            af[mi2][kc], bfv[ni][kc], acc[p * 2 + mi2][ni], 0, 0, 0);
            __builtin_amdgcn_s_setprio(0);
            if (p == P - 1) {
                // K-tile boundary: only tile t+1's loads are outstanding
                asm volatile("s_waitcnt vmcnt(0)" ::: "memory");
            }
            __builtin_amdgcn_s_barrier();
        }
    }

    // epilogue: C/D layout col=lane&15, row=g*4+reg
#pragma unroll
    for (int mi = 0; mi < MI; mi++) {
#pragma unroll
        for (int ni = 0; ni < NI; ni++) {
            const int col = bn + wc * (NI * 16) + ni * 16 + m;
            if (mode == 0) {
#pragma unroll
                for (int r = 0; r < 4; r++) {
                    const int row = bm + wr * (MI * 16) + mi * 16 + g * 4 + r;
                    C[(size_t)row * N + col] = acc[mi][ni][r];
                }
            } else {
                const int which = col >> 11;          // wave-uniform (64-col span)
                const int e = col & 2047;
                const int h = e >> 7;
                const int d = e & 127;
                if (which < 2) {
                    // q/k with fused RoPE: pair (even d, odd d) across lanes m, m^1
                    unsigned short* dst = (which == 0) ? qo : ko;
                    const int t2 = ((d >> 1) << 1);   // pair index *2
#pragma unroll
                    for (int r = 0; r < 4; r++) {
                        const int row = bm + wr * (MI * 16) + mi * 16 + g * 4 + r;
                        const int b = row >> 11;
                        const int l = row & 2047;
                        float val = acc[mi][ni][r];
                        const float prt = __shfl_xor(val, 1);
                        const float2 sc = *(const float2*)(rope + (size_t)l * HD + t2);
                        val = (m & 1) ? fmaf(val, sc.y, prt * sc.x)
                                      : fmaf(val, sc.y, -prt * sc.x);
                        dst[(((size_t)(b * NH + h)) * LSEQ + l) * HD + d] = f2bf(val);
                    }
                } else {
                    // v transposed: [B,H,HD,L], 4 consecutive l per lane -> ushort4
                    const int l0 = bm + wr * (MI * 16) + mi * 16 + g * 4;
                    const int b = l0 >> 11;
                    const int l = l0 & 2047;
                    ushort4 vv;
                    vv.x = f2bf(acc[mi][ni][0]);
                    vv.y = f2bf(acc[mi][ni][1]);
                    vv.z = f2bf(acc[mi][ni][2]);
                    vv.w = f2bf(acc[mi][ni][3]);
                    *(ushort4*)(vo + (((size_t)(b * NH + h)) * HD + d) * LSEQ + l) = vv;
                }
            }
        }
    }
}

// ---------------------------------------------------------------------------
// MFMA bf16 flash attention (causal), double-buffered K/V pipeline.
// (unchanged — verified passing; not the dominant dispatch)
// ---------------------------------------------------------------------------
#define PTILES 32     // LSEQ / 64
#define PS_STR 68

__global__ __launch_bounds__(256) void attn_kernel(
    const unsigned short* __restrict__ q, const unsigned short* __restrict__ k,
    const unsigned short* __restrict__ vT, unsigned short* __restrict__ y)
{
    __shared__ __align__(16) unsigned short Ks[2][64 * 128];  // 2x16 KB [key][d] swizzled
    __shared__ __align__(16) unsigned short Vs[2][64 * 128];  // 2x16 KB [d][key] swizzled
    __shared__ __align__(16) unsigned short Ps[64 * PS_STR];  // 8704 B

    const int tid = threadIdx.x;
    const int lane = tid & 63;
    const int w = tid >> 6;
    const int m = lane & 15;
    const int g = lane >> 4;
    const int bh = blockIdx.x;                 // 0..31 (B*H)
    const int qt = PTILES - 1 - blockIdx.y;    // heavy tiles dispatched first
    const int q0 = qt * 64;
    const size_t base = (size_t)bh * LSEQ * HD;   // also [bh][HD][LSEQ] base for vT
    const float scale = 0.08838834764831845f;  // 1/sqrt(128)
    const int bB = bh / NH;
    const int hh = bh % NH;
    const int sw = m & 7;   // read-side swizzle key

    // stage K+V tile (swizzled source chunks, lane-linear LDS dest)
    auto stage = [&](int buf, int kb0) {
        const unsigned short* ksrc = k + base + (size_t)kb0 * HD;
#pragma unroll
        for (int i = 0; i < 4; i++) {
            const int idx = i * 256 + tid;
            const int row = idx >> 4;                 // 0..63
            const int c = (idx & 15) ^ (row & 7);     // source chunk
            load_lds16(ksrc + (size_t)row * HD + c * 8, &Ks[buf][idx * 8]);
        }
#pragma unroll
        for (int i = 0; i < 4; i++) {
            const int idx = i * 256 + tid;
            const int d = idx >> 3;                   // 0..127
            const int c = (idx & 7) ^ (d & 7);
            load_lds16(vT + base + (size_t)d * LSEQ + kb0 + c * 8, &Vs[buf][idx * 8]);
        }
    };

    // ---- Q fragments in registers (row = q0 + w*16 + m) ----
    bf16x8 aq[4];
    {
        const unsigned short* qrow = q + base + (size_t)(q0 + w * 16 + m) * HD;
#pragma unroll
        for (int kc = 0; kc < 4; kc++)
            aq[kc] = *(const bf16x8*)(qrow + kc * 32 + g * 8);
    }

    f32x4 o[8];
#pragma unroll
    for (int i = 0; i < 8; i++) o[i] = (f32x4){0.f, 0.f, 0.f, 0.f};
    float mprev[4], lsum[4];
#pragma unroll
    for (int r = 0; r < 4; r++) { mprev[r] = -1e30f; lsum[r] = 0.f; }

    // prologue: stage tile 0 into buffer 0
    stage(0, 0);
    int cur = 0;

    for (int kt = 0; kt <= qt; kt++) {
        const int k0 = kt * 64;

        // drains prefetch of buf[cur] (vmcnt(0) emitted before barrier) and
        // orders prior-iteration LDS reads before this iteration's staging
        __syncthreads();

        // issue next-tile prefetch now; it stays in flight through compute
        if (kt < qt) stage(cur ^ 1, k0 + 64);

        const unsigned short* Kc = Ks[cur];
        const unsigned short* Vc = Vs[cur];

        // ---- S = Q K^T (16 rows x 64 keys per wave) ----
        f32x4 s[4];
#pragma unroll
        for (int n = 0; n < 4; n++) {
            f32x4 acc = (f32x4){0.f, 0.f, 0.f, 0.f};
#pragma unroll
            for (int kc = 0; kc < 4; kc++) {
                const int row = n * 16 + m;
                bf16x8 bk = *(const bf16x8*)&Kc[(row * 16 + ((kc * 4 + g) ^ sw)) * 8];
                acc = __builtin_amdgcn_mfma_f32_16x16x32_bf16(aq[kc], bk, acc, 0, 0, 0);
            }
            s[n] = acc;
        }

        // ---- scale + causal mask (only the diagonal tile) ----
        const int rowg = q0 + w * 16 + g * 4;
        if (kt == qt) {
#pragma unroll
            for (int n = 0; n < 4; n++) {
                const int col = k0 + n * 16 + m;
#pragma unroll
                for (int r = 0; r < 4; r++) {
                    const float val = s[n][r] * scale;
                    s[n][r] = (col <= rowg + r) ? val : -1e30f;
                }
            }
        } else {
#pragma unroll
            for (int n = 0; n < 4; n++)
#pragma unroll
                for (int r = 0; r < 4; r++) s[n][r] *= scale;
        }

        // ---- online softmax ----
        float al[4];
#pragma unroll
        for (int r = 0; r < 4; r++) {
            float v0 = fmaxf(fmaxf(s[0][r], s[1][r]), fmaxf(s[2][r], s[3][r]));
            v0 = fmaxf(v0, __shfl_xor(v0, 1));
            v0 = fmaxf(v0, __shfl_xor(v0, 2));
            v0 = fmaxf(v0, __shfl_xor(v0, 4));
            v0 = fmaxf(v0, __shfl_xor(v0, 8));
            const float mn = fmaxf(mprev[r], v0);
            al[r] = __expf(mprev[r] - mn);
            mprev[r] = mn;
        }
#pragma unroll
        for (int r = 0; r < 4; r++) {
            float sum = 0.f;
#pragma unroll
            for (int n = 0; n < 4; n++) {
                const float p = __expf(s[n][r] - mprev[r]);
                sum += p;
                Ps[(w * 16 + g * 4 + r) * PS_STR + n * 16 + m] = f2bf(p);
            }
            sum += __shfl_xor(sum, 1);
            sum += __shfl_xor(sum, 2);
            sum += __shfl_xor(sum, 4);
            sum += __shfl_xor(sum, 8);
            lsum[r] = lsum[r] * al[r] + sum;
        }

        // ---- O = O*alpha + P V ----
#pragma unroll
        for (int dc = 0; dc < 8; dc++)
#pragma unroll
            for (int r = 0; r < 4; r++) o[dc][r] *= al[r];

        // per-wave private Ps rows; same-wave DS ordering suffices (no barrier)
        bf16x8 ap[2];
#pragma unroll
        for (int kk = 0; kk < 2; kk++)
            ap[kk] = *(const bf16x8*)&Ps[(w * 16 + m) * PS_STR + kk * 32 + g * 8];
#pragma unroll
        for (int dc = 0; dc < 8; dc++) {
#pragma unroll
            for (int kk = 0; kk < 2; kk++) {
                const int row = dc * 16 + m;
                bf16x8 bv = *(const bf16x8*)&Vc[(row * 8 + ((kk * 4 + g) ^ sw)) * 8];
                o[dc] = __builtin_amdgcn_mfma_f32_16x16x32_bf16(ap[kk], bv, o[dc], 0, 0, 0);
            }
        }

        cur ^= 1;
    }

    // ---- epilogue: normalize, write y bf16 [B, L, H, HD] ----
#pragma unroll
    for (int r = 0; r < 4; r++) {
        const float inv = 1.f / lsum[r];
        const int lrow = q0 + w * 16 + g * 4 + r;
        unsigned short* dst = y + (((size_t)bB * LSEQ + lrow) * NH + hh) * HD;
#pragma unroll
        for (int dc = 0; dc < 8; dc++)
            dst[dc * 16 + m] = f2bf(o[dc][r] * inv);
    }
}

// ---------------------------------------------------------------------------
extern "C" void kernel_launch(void* const* d_in, const int* in_sizes, int n_in,
                              void* d_out, int out_size, void* d_ws, size_t ws_size,
                              hipStream_t stream) {
    const float* x      = (const float*)d_in[0];
    const float* rope   = (const float*)d_in[1];
    const float* w_attn = (const float*)d_in[2];
    const float* w_proj = (const float*)d_in[3];
    float* out = (float*)d_out;
    unsigned short* ws = (unsigned short*)d_ws;

    const size_t per = (size_t)BATCH * NH * LSEQ * HD;  // 8,388,608
    unsigned short* qb  = ws;
    unsigned short* kb  = ws + per;
    unsigned short* vb  = ws + 2 * per;   // transposed layout [B,H,HD,L]
    unsigned short* yb  = ws + 3 * per;
    unsigned short* xb  = ws + 4 * per;
    unsigned short* wab = xb + (size_t)N1;
    unsigned short* wpb = wab + (size_t)N2;

    const int M = BATCH * LSEQ;  // 4096

    // 0) cast inputs to bf16
    const int cast_blocks = (N1 + N2 + N3) / 4 / 256;
    cast_bf16_kernel<<<cast_blocks, 256, 0, stream>>>(x, w_attn, w_proj, xb, wab, wpb);

    // 1) QKV projection: 128x256 tile -> grid (24,32) = 768 blocks = 3 exact
    //    rounds of 256 CUs (round-5's 384 wasted 25% on tail quantization)
    dim3 g1(3 * EMB / 256, M / 128);  // (24, 32) -> nwg 768 (%8==0)
    gemm_bt_bf16<4, 4><<<g1, 512, 0, stream>>>(xb, wab, rope, nullptr, qb, kb, vb,
                                               M, 3 * EMB, EMB, 1);

    // 2) causal flash attention -> y bf16 (LPT grid: heavy q-tiles first)
    dim3 ga(BATCH * NH, PTILES);  // (32, 32)
    attn_kernel<<<ga, 256, 0, stream>>>(qb, kb, vb, yb);

    // 3) output projection: 256x128 tile -> grid (16,16) = 256 blocks = 1 round
    dim3 g2(EMB / 128, M / 256);  // (16, 16) -> nwg 256 (%8==0)
    gemm_bt_bf16<8, 2><<<g2, 512, 0, stream>>>(yb, wpb, nullptr, out,
                                               nullptr, nullptr, nullptr, M, EMB, EMB, 0);
}

// Round 7
// 417.050 us; speedup vs baseline: 1.0804x; 1.0804x over previous
//
#include <hip/hip_runtime.h>
#include <math.h>

#define BATCH 2
#define LSEQ  2048
#define EMB   2048
#define NH    16
#define HD    128

typedef __attribute__((ext_vector_type(8))) short bf16x8;
typedef __attribute__((ext_vector_type(8))) unsigned short u16x8;
typedef __attribute__((ext_vector_type(4))) float f32x4;

static __device__ __forceinline__ unsigned short f2bf(float f) {
    unsigned u = __float_as_uint(f);
    u += 0x7fffu + ((u >> 16) & 1u);
    return (unsigned short)(u >> 16);
}

// async global->LDS, 16 bytes per lane; LDS dest must be wave-uniform base + lane*16
static __device__ __forceinline__ void load_lds16(const void* g, void* l) {
    __builtin_amdgcn_global_load_lds(
        (const __attribute__((address_space(1))) void*)g,
        (__attribute__((address_space(3))) void*)l, 16, 0, 0);
}

// ---------------------------------------------------------------------------
// cast fp32 -> bf16 for x, w_attn, w_proj
// ---------------------------------------------------------------------------
#define N1 (BATCH * LSEQ * EMB)      // 8388608  (x)
#define N2 (3 * EMB * EMB)           // 12582912 (w_attn)
#define N3 (EMB * EMB)               // 4194304  (w_proj)

__global__ __launch_bounds__(256) void cast_bf16_kernel(
    const float* __restrict__ x, const float* __restrict__ wa,
    const float* __restrict__ wp,
    unsigned short* __restrict__ xb, unsigned short* __restrict__ wab,
    unsigned short* __restrict__ wpb)
{
    size_t i4 = ((size_t)blockIdx.x * 256 + threadIdx.x) * 4;
    const float* src;
    unsigned short* dst;
    size_t off;
    if (i4 < (size_t)N1) { src = x; dst = xb; off = i4; }
    else if (i4 < (size_t)N1 + N2) { src = wa; dst = wab; off = i4 - N1; }
    else { src = wp; dst = wpb; off = i4 - N1 - N2; }
    float4 f = *(const float4*)(src + off);
    ushort4 u;
    u.x = f2bf(f.x); u.y = f2bf(f.y); u.z = f2bf(f.z); u.w = f2bf(f.w);
    *(ushort4*)(dst + off) = u;
}

// ---------------------------------------------------------------------------
// MFMA bf16 GEMM, 256 x (NI*64) tile, 512 threads = 8 waves (2M x 4N),
// per-wave 128 x NI*16 output. BK=64, double-buffered LDS.
//
// K-tile body (reads buf rd=t&1, stages t+1 into rd^1) — counted-lgkm
// register pipeline, ONE barrier per tile:
//   stage(t+1)  (8 vmem issues; lands ~2500cy later, drained by boundary vmcnt)
//   read all B-frags + A-frags(phase0)  -> lgkmcnt(0), sched_barrier
//   p=0: issue A-frags(1) ds_reads            ; 16 MFMA on A(0)   <- reads
//   p=1: issue A-frags(2) ; lgkmcnt(4) ; sb ; 16 MFMA on A(1)        overlap
//   p=2: issue A-frags(3) ; lgkmcnt(4) ; sb ; 16 MFMA on A(2)        MFMAs
//   p=3:                    lgkmcnt(0) ; sb ; 16 MFMA on A(3)
//   vmcnt(0)  (stage issued a full tile ago -> ~free)
//   s_barrier (publishes buf swap; all reads of rd were drained above)
// Rationale: LDS-read port (~2300cy/tile/CU) and MFMA pipe (~2480cy) are
// co-equal costs; R5's per-phase barrier+lgkm(0) serialized them (=~7500cy
// observed). This overlaps them (rule #18: sched_barrier(0) after each
// counted lgkmcnt so MFMAs can't hoist past the wait).
// Hazards: stage writes rd^1 only; every wave's reads of rd are drained by
// its own waitcnts before its boundary barrier -> overwrite of rd next tile
// is safe. One barrier/tile bounds wave drift to a tile; buffers differ.
// LDS chunk layout XOR-swizzled (slot row*8+c' holds chunk c'^(row&7));
// reads swizzle identically -> measured 0 bank conflicts.
// XCD-aware bijective block swizzle (nwg % 8 == 0 at all call sites).
// mode 0: C fp32 row-major [M,N]
// mode 1: q/k scattered bf16 into [B,H,L,HD] WITH RoPE fused;
//         v scattered bf16 TRANSPOSED into [B,H,HD,L] (packed ushort4 along L)
// ---------------------------------------------------------------------------
template<int NI>   // per-wave N fragments: 4 -> BN=256 (QKV), 2 -> BN=128 (proj)
__global__ __launch_bounds__(512, 2) void gemm_bt_bf16(
    const unsigned short* __restrict__ A, const unsigned short* __restrict__ B,
    const float* __restrict__ rope,
    float* __restrict__ C,
    unsigned short* __restrict__ qo, unsigned short* __restrict__ ko,
    unsigned short* __restrict__ vo,
    int M, int N, int K, int mode)
{
    constexpr int BN = NI * 64;
    __shared__ __align__(16) unsigned short As[2][256 * 64];   // 2 x 32 KB
    __shared__ __align__(16) unsigned short Bs[2][BN * 64];    // 2 x NI*8 KB

    const int tid = threadIdx.x;
    const int lane = tid & 63;
    const int w = tid >> 6;      // 0..7
    const int m = lane & 15;
    const int g = lane >> 4;
    const int wr = w >> 2;       // 0..1 : M half (128 rows)
    const int wc = w & 3;        // 0..3 : N quadrant (NI*16 cols)
    const int sw = m & 7;        // read-side swizzle key

    // XCD-aware swizzle (nwg 384 / 256, both %8==0)
    const int nwgx = gridDim.x;
    const int lin = blockIdx.y * nwgx + blockIdx.x;
    const int cpx = (nwgx * gridDim.y) >> 3;
    const int swz = (lin & 7) * cpx + (lin >> 3);
    const int bm = (swz / nwgx) * 256;
    const int bn = (swz % nwgx) * BN;

    // stage whole K-tile (A: 256x64, B: BNx64) into buffer `buf`
    auto stage = [&](int buf, int k0) {
#pragma unroll
        for (int i = 0; i < 4; i++) {
            const int idx = i * 512 + tid;          // 0..2047
            const int row = idx >> 3;               // 0..255
            const int c = (idx & 7) ^ (row & 7);
            load_lds16(A + (size_t)(bm + row) * K + k0 + c * 8, &As[buf][idx * 8]);
        }
#pragma unroll
        for (int i = 0; i < NI; i++) {
            const int idx = i * 512 + tid;          // 0..BN*8-1
            const int row = idx >> 3;
            const int c = (idx & 7) ^ (row & 7);
            load_lds16(B + (size_t)(bn + row) * K + k0 + c * 8, &Bs[buf][idx * 8]);
        }
    };

    f32x4 acc[8][NI];
#pragma unroll
    for (int mi = 0; mi < 8; mi++)
#pragma unroll
        for (int ni = 0; ni < NI; ni++) acc[mi][ni] = (f32x4){0.f, 0.f, 0.f, 0.f};

    const int nt = K >> 6;

    // prologue
    stage(0, 0);
    asm volatile("s_waitcnt vmcnt(0)" ::: "memory");
    __builtin_amdgcn_s_barrier();

    for (int t = 0; t < nt; t++) {
        const int rd = t & 1;
        const unsigned short* Ac = As[rd];
        const unsigned short* Bc = Bs[rd];

        if (t + 1 < nt) stage(rd ^ 1, (t + 1) * 64);

        // A-frag reader for phase p into a named 2x2 set (static indexing)
        bf16x8 afA[2][2], afB[2][2];
#define READ_AF(dstv, pconst)                                                   \
        {                                                                       \
            _Pragma("unroll")                                                   \
            for (int mi2 = 0; mi2 < 2; mi2++) {                                 \
                const int row = wr * 128 + ((pconst) * 2 + mi2) * 16 + m;       \
                _Pragma("unroll")                                               \
                for (int kc = 0; kc < 2; kc++)                                  \
                    dstv[mi2][kc] = *(const bf16x8*)&Ac[(row * 8 +              \
                        ((kc * 4 + g) ^ sw)) * 8];                              \
            }                                                                   \
        }
#define MFMA_PH(srcv, pconst)                                                   \
        {                                                                       \
            _Pragma("unroll")                                                   \
            for (int mi2 = 0; mi2 < 2; mi2++)                                   \
                _Pragma("unroll")                                               \
                for (int ni = 0; ni < NI; ni++)                                 \
                    _Pragma("unroll")                                           \
                    for (int kc = 0; kc < 2; kc++)                              \
                        acc[(pconst) * 2 + mi2][ni] =                           \
                            __builtin_amdgcn_mfma_f32_16x16x32_bf16(            \
                                srcv[mi2][kc], bfv[ni][kc],                     \
                                acc[(pconst) * 2 + mi2][ni], 0, 0, 0);          \
        }

        // tile-start reads: all B-frags + phase-0 A-frags
        bf16x8 bfv[NI][2];
#pragma unroll
        for (int ni = 0; ni < NI; ni++) {
            const int row = wc * (NI * 16) + ni * 16 + m;
#pragma unroll
            for (int kc = 0; kc < 2; kc++)
                bfv[ni][kc] = *(const bf16x8*)&Bc[(row * 8 + ((kc * 4 + g) ^ sw)) * 8];
        }
        READ_AF(afA, 0)
        asm volatile("s_waitcnt lgkmcnt(0)" ::: "memory");
        __builtin_amdgcn_sched_barrier(0);

        __builtin_amdgcn_s_setprio(1);
        // p=0: prefetch A(1), compute A(0)  (A(0)+B already resident)
        READ_AF(afB, 1)
        MFMA_PH(afA, 0)
        // p=1: prefetch A(2); wait A(1) (<=4 outstanding = the just-issued A(2))
        READ_AF(afA, 2)
        asm volatile("s_waitcnt lgkmcnt(4)" ::: "memory");
        __builtin_amdgcn_sched_barrier(0);
        MFMA_PH(afB, 1)
        // p=2: prefetch A(3); wait A(2)
        READ_AF(afB, 3)
        asm volatile("s_waitcnt lgkmcnt(4)" ::: "memory");
        __builtin_amdgcn_sched_barrier(0);
        MFMA_PH(afA, 2)
        // p=3: wait A(3)
        asm volatile("s_waitcnt lgkmcnt(0)" ::: "memory");
        __builtin_amdgcn_sched_barrier(0);
        MFMA_PH(afB, 3)
        __builtin_amdgcn_s_setprio(0);

        // boundary: stage(t+1) was issued a full tile of compute ago
        asm volatile("s_waitcnt vmcnt(0)" ::: "memory");
        __builtin_amdgcn_s_barrier();
#undef READ_AF
#undef MFMA_PH
    }

    // epilogue: C/D layout col=lane&15, row=g*4+reg
#pragma unroll
    for (int mi = 0; mi < 8; mi++) {
#pragma unroll
        for (int ni = 0; ni < NI; ni++) {
            const int col = bn + wc * (NI * 16) + ni * 16 + m;
            if (mode == 0) {
#pragma unroll
                for (int r = 0; r < 4; r++) {
                    const int row = bm + wr * 128 + mi * 16 + g * 4 + r;
                    C[(size_t)row * N + col] = acc[mi][ni][r];
                }
            } else {
                const int which = col >> 11;          // wave-uniform (64-col span)
                const int e = col & 2047;
                const int h = e >> 7;
                const int d = e & 127;
                if (which < 2) {
                    // q/k with fused RoPE: pair (even d, odd d) across lanes m, m^1
                    unsigned short* dst = (which == 0) ? qo : ko;
                    const int t2 = ((d >> 1) << 1);   // pair index *2
#pragma unroll
                    for (int r = 0; r < 4; r++) {
                        const int row = bm + wr * 128 + mi * 16 + g * 4 + r;
                        const int b = row >> 11;
                        const int l = row & 2047;
                        float val = acc[mi][ni][r];
                        const float prt = __shfl_xor(val, 1);
                        const float2 sc = *(const float2*)(rope + (size_t)l * HD + t2);
                        val = (m & 1) ? fmaf(val, sc.y, prt * sc.x)
                                      : fmaf(val, sc.y, -prt * sc.x);
                        dst[(((size_t)(b * NH + h)) * LSEQ + l) * HD + d] = f2bf(val);
                    }
                } else {
                    // v transposed: [B,H,HD,L], 4 consecutive l per lane -> ushort4
                    const int l0 = bm + wr * 128 + mi * 16 + g * 4;
                    const int b = l0 >> 11;
                    const int l = l0 & 2047;
                    ushort4 vv;
                    vv.x = f2bf(acc[mi][ni][0]);
                    vv.y = f2bf(acc[mi][ni][1]);
                    vv.z = f2bf(acc[mi][ni][2]);
                    vv.w = f2bf(acc[mi][ni][3]);
                    *(ushort4*)(vo + (((size_t)(b * NH + h)) * HD + d) * LSEQ + l) = vv;
                }
            }
        }
    }
}

// ---------------------------------------------------------------------------
// MFMA bf16 flash attention (causal), double-buffered K/V pipeline.
// (unchanged — verified passing)
// ---------------------------------------------------------------------------
#define PTILES 32     // LSEQ / 64
#define PS_STR 68

__global__ __launch_bounds__(256) void attn_kernel(
    const unsigned short* __restrict__ q, const unsigned short* __restrict__ k,
    const unsigned short* __restrict__ vT, unsigned short* __restrict__ y)
{
    __shared__ __align__(16) unsigned short Ks[2][64 * 128];  // 2x16 KB [key][d] swizzled
    __shared__ __align__(16) unsigned short Vs[2][64 * 128];  // 2x16 KB [d][key] swizzled
    __shared__ __align__(16) unsigned short Ps[64 * PS_STR];  // 8704 B

    const int tid = threadIdx.x;
    const int lane = tid & 63;
    const int w = tid >> 6;
    const int m = lane & 15;
    const int g = lane >> 4;
    const int bh = blockIdx.x;                 // 0..31 (B*H)
    const int qt = PTILES - 1 - blockIdx.y;    // heavy tiles dispatched first
    const int q0 = qt * 64;
    const size_t base = (size_t)bh * LSEQ * HD;   // also [bh][HD][LSEQ] base for vT
    const float scale = 0.08838834764831845f;  // 1/sqrt(128)
    const int bB = bh / NH;
    const int hh = bh % NH;
    const int sw = m & 7;   // read-side swizzle key

    // stage K+V tile (swizzled source chunks, lane-linear LDS dest)
    auto stage = [&](int buf, int kb0) {
        const unsigned short* ksrc = k + base + (size_t)kb0 * HD;
#pragma unroll
        for (int i = 0; i < 4; i++) {
            const int idx = i * 256 + tid;
            const int row = idx >> 4;                 // 0..63
            const int c = (idx & 15) ^ (row & 7);     // source chunk
            load_lds16(ksrc + (size_t)row * HD + c * 8, &Ks[buf][idx * 8]);
        }
#pragma unroll
        for (int i = 0; i < 4; i++) {
            const int idx = i * 256 + tid;
            const int d = idx >> 3;                   // 0..127
            const int c = (idx & 7) ^ (d & 7);
            load_lds16(vT + base + (size_t)d * LSEQ + kb0 + c * 8, &Vs[buf][idx * 8]);
        }
    };

    // ---- Q fragments in registers (row = q0 + w*16 + m) ----
    bf16x8 aq[4];
    {
        const unsigned short* qrow = q + base + (size_t)(q0 + w * 16 + m) * HD;
#pragma unroll
        for (int kc = 0; kc < 4; kc++)
            aq[kc] = *(const bf16x8*)(qrow + kc * 32 + g * 8);
    }

    f32x4 o[8];
#pragma unroll
    for (int i = 0; i < 8; i++) o[i] = (f32x4){0.f, 0.f, 0.f, 0.f};
    float mprev[4], lsum[4];
#pragma unroll
    for (int r = 0; r < 4; r++) { mprev[r] = -1e30f; lsum[r] = 0.f; }

    // prologue: stage tile 0 into buffer 0
    stage(0, 0);
    int cur = 0;

    for (int kt = 0; kt <= qt; kt++) {
        const int k0 = kt * 64;

        // drains prefetch of buf[cur] (vmcnt(0) emitted before barrier) and
        // orders prior-iteration LDS reads before this iteration's staging
        __syncthreads();

        // issue next-tile prefetch now; it stays in flight through compute
        if (kt < qt) stage(cur ^ 1, k0 + 64);

        const unsigned short* Kc = Ks[cur];
        const unsigned short* Vc = Vs[cur];

        // ---- S = Q K^T (16 rows x 64 keys per wave) ----
        f32x4 s[4];
#pragma unroll
        for (int n = 0; n < 4; n++) {
            f32x4 acc = (f32x4){0.f, 0.f, 0.f, 0.f};
#pragma unroll
            for (int kc = 0; kc < 4; kc++) {
                const int row = n * 16 + m;
                bf16x8 bk = *(const bf16x8*)&Kc[(row * 16 + ((kc * 4 + g) ^ sw)) * 8];
                acc = __builtin_amdgcn_mfma_f32_16x16x32_bf16(aq[kc], bk, acc, 0, 0, 0);
            }
            s[n] = acc;
        }

        // ---- scale + causal mask (only the diagonal tile) ----
        const int rowg = q0 + w * 16 + g * 4;
        if (kt == qt) {
#pragma unroll
            for (int n = 0; n < 4; n++) {
                const int col = k0 + n * 16 + m;
#pragma unroll
                for (int r = 0; r < 4; r++) {
                    const float val = s[n][r] * scale;
                    s[n][r] = (col <= rowg + r) ? val : -1e30f;
                }
            }
        } else {
#pragma unroll
            for (int n = 0; n < 4; n++)
#pragma unroll
                for (int r = 0; r < 4; r++) s[n][r] *= scale;
        }

        // ---- online softmax ----
        float al[4];
#pragma unroll
        for (int r = 0; r < 4; r++) {
            float v0 = fmaxf(fmaxf(s[0][r], s[1][r]), fmaxf(s[2][r], s[3][r]));
            v0 = fmaxf(v0, __shfl_xor(v0, 1));
            v0 = fmaxf(v0, __shfl_xor(v0, 2));
            v0 = fmaxf(v0, __shfl_xor(v0, 4));
            v0 = fmaxf(v0, __shfl_xor(v0, 8));
            const float mn = fmaxf(mprev[r], v0);
            al[r] = __expf(mprev[r] - mn);
            mprev[r] = mn;
        }
#pragma unroll
        for (int r = 0; r < 4; r++) {
            float sum = 0.f;
#pragma unroll
            for (int n = 0; n < 4; n++) {
                const float p = __expf(s[n][r] - mprev[r]);
                sum += p;
                Ps[(w * 16 + g * 4 + r) * PS_STR + n * 16 + m] = f2bf(p);
            }
            sum += __shfl_xor(sum, 1);
            sum += __shfl_xor(sum, 2);
            sum += __shfl_xor(sum, 4);
            sum += __shfl_xor(sum, 8);
            lsum[r] = lsum[r] * al[r] + sum;
        }

        // ---- O = O*alpha + P V ----
#pragma unroll
        for (int dc = 0; dc < 8; dc++)
#pragma unroll
            for (int r = 0; r < 4; r++) o[dc][r] *= al[r];

        // per-wave private Ps rows; same-wave DS ordering suffices (no barrier)
        bf16x8 ap[2];
#pragma unroll
        for (int kk = 0; kk < 2; kk++)
            ap[kk] = *(const bf16x8*)&Ps[(w * 16 + m) * PS_STR + kk * 32 + g * 8];
#pragma unroll
        for (int dc = 0; dc < 8; dc++) {
#pragma unroll
            for (int kk = 0; kk < 2; kk++) {
                const int row = dc * 16 + m;
                bf16x8 bv = *(const bf16x8*)&Vc[(row * 8 + ((kk * 4 + g) ^ sw)) * 8];
                o[dc] = __builtin_amdgcn_mfma_f32_16x16x32_bf16(ap[kk], bv, o[dc], 0, 0, 0);
            }
        }

        cur ^= 1;
    }

    // ---- epilogue: normalize, write y bf16 [B, L, H, HD] ----
#pragma unroll
    for (int r = 0; r < 4; r++) {
        const float inv = 1.f / lsum[r];
        const int lrow = q0 + w * 16 + g * 4 + r;
        unsigned short* dst = y + (((size_t)bB * LSEQ + lrow) * NH + hh) * HD;
#pragma unroll
        for (int dc = 0; dc < 8; dc++)
            dst[dc * 16 + m] = f2bf(o[dc][r] * inv);
    }
}

// ---------------------------------------------------------------------------
extern "C" void kernel_launch(void* const* d_in, const int* in_sizes, int n_in,
                              void* d_out, int out_size, void* d_ws, size_t ws_size,
                              hipStream_t stream) {
    const float* x      = (const float*)d_in[0];
    const float* rope   = (const float*)d_in[1];
    const float* w_attn = (const float*)d_in[2];
    const float* w_proj = (const float*)d_in[3];
    float* out = (float*)d_out;
    unsigned short* ws = (unsigned short*)d_ws;

    const size_t per = (size_t)BATCH * NH * LSEQ * HD;  // 8,388,608
    unsigned short* qb  = ws;
    unsigned short* kb  = ws + per;
    unsigned short* vb  = ws + 2 * per;   // transposed layout [B,H,HD,L]
    unsigned short* yb  = ws + 3 * per;
    unsigned short* xb  = ws + 4 * per;
    unsigned short* wab = xb + (size_t)N1;
    unsigned short* wpb = wab + (size_t)N2;

    const int M = BATCH * LSEQ;  // 4096

    // 0) cast inputs to bf16
    const int cast_blocks = (N1 + N2 + N3) / 4 / 256;
    cast_bf16_kernel<<<cast_blocks, 256, 0, stream>>>(x, w_attn, w_proj, xb, wab, wpb);

    // 1) QKV projection (256x256, counted-lgkm pipeline) + fused RoPE
    dim3 g1(3 * EMB / 256, M / 256);  // (24, 16) -> nwg 384 (%8==0)
    gemm_bt_bf16<4><<<g1, 512, 0, stream>>>(xb, wab, rope, nullptr, qb, kb, vb,
                                            M, 3 * EMB, EMB, 1);

    // 2) causal flash attention -> y bf16 (LPT grid: heavy q-tiles first)
    dim3 ga(BATCH * NH, PTILES);  // (32, 32)
    attn_kernel<<<ga, 256, 0, stream>>>(qb, kb, vb, yb);

    // 3) output projection (256x128, counted-lgkm pipeline) -> fp32 out
    dim3 g2(EMB / 128, M / 256);  // (16, 16) -> nwg 256 (%8==0), full GPU
    gemm_bt_bf16<2><<<g2, 512, 0, stream>>>(yb, wpb, nullptr, out,
                                            nullptr, nullptr, nullptr, M, EMB, EMB, 0);
}

// Round 9
// 402.631 us; speedup vs baseline: 1.1191x; 1.0358x over previous
//
#include <hip/hip_runtime.h>
#include <math.h>

#define BATCH 2
#define LSEQ  2048
#define EMB   2048
#define NH    16
#define HD    128

typedef __attribute__((ext_vector_type(8))) short bf16x8;
typedef __attribute__((ext_vector_type(8))) unsigned short u16x8;
typedef __attribute__((ext_vector_type(4))) float f32x4;

static __device__ __forceinline__ unsigned short f2bf(float f) {
    unsigned u = __float_as_uint(f);
    u += 0x7fffu + ((u >> 16) & 1u);
    return (unsigned short)(u >> 16);
}

// async global->LDS, 16 bytes per lane; LDS dest must be wave-uniform base + lane*16
static __device__ __forceinline__ void load_lds16(const void* g, void* l) {
    __builtin_amdgcn_global_load_lds(
        (const __attribute__((address_space(1))) void*)g,
        (__attribute__((address_space(3))) void*)l, 16, 0, 0);
}

// ---------------------------------------------------------------------------
// cast fp32 -> bf16 for x, w_attn, w_proj
// ---------------------------------------------------------------------------
#define N1 (BATCH * LSEQ * EMB)      // 8388608  (x)
#define N2 (3 * EMB * EMB)           // 12582912 (w_attn)
#define N3 (EMB * EMB)               // 4194304  (w_proj)

__global__ __launch_bounds__(256) void cast_bf16_kernel(
    const float* __restrict__ x, const float* __restrict__ wa,
    const float* __restrict__ wp,
    unsigned short* __restrict__ xb, unsigned short* __restrict__ wab,
    unsigned short* __restrict__ wpb)
{
    size_t i4 = ((size_t)blockIdx.x * 256 + threadIdx.x) * 4;
    const float* src;
    unsigned short* dst;
    size_t off;
    if (i4 < (size_t)N1) { src = x; dst = xb; off = i4; }
    else if (i4 < (size_t)N1 + N2) { src = wa; dst = wab; off = i4 - N1; }
    else { src = wp; dst = wpb; off = i4 - N1 - N2; }
    float4 f = *(const float4*)(src + off);
    ushort4 u;
    u.x = f2bf(f.x); u.y = f2bf(f.y); u.z = f2bf(f.z); u.w = f2bf(f.w);
    *(ushort4*)(dst + off) = u;
}

// ---------------------------------------------------------------------------
// QKV GEMM engine — R5's 4-phase-per-K-tile schedule, verbatim (passed, 150.6us).
// Tile: 256 x (NI*64), 512 threads = 8 waves (2M x 4N); per-wave 128 x NI*16.
// BK=64, double-buffered LDS. Per K-tile t (reads buf rd=t&1, stages t+1 into
// rd^1), 4 phases, each:
//   { ds_read A-frag pair (+all B-frags in phase 0) ; issue half-tile stage }
//   s_barrier ; s_waitcnt lgkmcnt(0) ; setprio(1) ; 8*NI MFMA ; setprio(0)
//   [phase 3 only: s_waitcnt vmcnt(0)]
//   s_barrier
// LDS chunk layout XOR-swizzled (slot row*8+c' holds chunk c'^(row&7)); reads
// swizzle identically -> measured 0 bank conflicts.
// XCD-aware bijective block swizzle (nwg % 8 == 0).
// mode 1: q/k scattered bf16 into [B,H,L,HD] WITH RoPE fused;
//         v scattered bf16 TRANSPOSED into [B,H,HD,L] (packed ushort4 along L)
// ---------------------------------------------------------------------------
template<int NI>   // per-wave N fragments: 4 -> BN=256 (QKV)
__global__ __launch_bounds__(512, 2) void gemm_bt_bf16(
    const unsigned short* __restrict__ A, const unsigned short* __restrict__ B,
    const float* __restrict__ rope,
    float* __restrict__ C,
    unsigned short* __restrict__ qo, unsigned short* __restrict__ ko,
    unsigned short* __restrict__ vo,
    int M, int N, int K, int mode)
{
    __shared__ __align__(16) unsigned short As[2][256 * 64];       // 2 x 32 KB
    __shared__ __align__(16) unsigned short Bs[2][NI * 64 * 64];   // 2 x NI*8 KB

    const int tid = threadIdx.x;
    const int lane = tid & 63;
    const int w = tid >> 6;      // 0..7
    const int m = lane & 15;
    const int g = lane >> 4;
    const int wr = w >> 2;       // 0..1 : M half (128 rows)
    const int wc = w & 3;        // 0..3 : N quadrant (NI*16 cols)
    const int sw = m & 7;        // read-side swizzle key

    const int nwgx = gridDim.x;
    const int lin = blockIdx.y * nwgx + blockIdx.x;
    const int cpx = (nwgx * gridDim.y) >> 3;
    const int swz = (lin & 7) * cpx + (lin >> 3);
    const int bm = (swz / nwgx) * 256;
    const int bn = (swz % nwgx) * (NI * 64);

    // Stage one half-tile (128 rows x 64 cols) into buffer `buf` at K-offset k0.
    auto stage_half = [&](int buf, int k0, int h) {
        const bool isA = (h < 2);
        const unsigned short* S = isA ? A : B;
        const int rbase = isA ? ((h & 1) * 128) : ((h - 2) * 128);
        unsigned short* L = isA ? &As[buf][rbase * 64] : &Bs[buf][(h - 2) * 128 * 64];
        const size_t gb = isA ? (size_t)bm : (size_t)bn;
#pragma unroll
        for (int i = 0; i < 2; i++) {
            const int idx = i * 512 + tid;          // 0..1023 chunk within half
            const int row = idx >> 3;               // 0..127
            const int c = (idx & 7) ^ (row & 7);    // swizzled source chunk
            load_lds16(S + (gb + rbase + row) * (size_t)K + k0 + c * 8, L + idx * 8);
        }
    };

    f32x4 acc[8][NI];
#pragma unroll
    for (int mi = 0; mi < 8; mi++)
#pragma unroll
        for (int ni = 0; ni < NI; ni++) acc[mi][ni] = (f32x4){0.f, 0.f, 0.f, 0.f};

    const int nt = K >> 6;   // K / 64
    const int NH_HALF = 2 + NI / 2;   // half-tiles per K-tile

    // prologue: stage tile 0 fully, drain, publish
#pragma unroll
    for (int h = 0; h < 4; h++)
        if (h < NH_HALF) stage_half(0, 0, h);
    asm volatile("s_waitcnt vmcnt(0)" ::: "memory");
    __builtin_amdgcn_s_barrier();

    for (int t = 0; t < nt; t++) {
        const int rd = t & 1;
        const int wrn = rd ^ 1;
        const int k1 = (t + 1) * 64;
        const unsigned short* Ac = As[rd];
        const unsigned short* Bc = Bs[rd];
        const bool pre = (t + 1 < nt);

        bf16x8 bfv[NI][2];

#pragma unroll
        for (int p = 0; p < 4; p++) {
            // ds_read this phase's A-fragment pair
            bf16x8 af[2][2];
#pragma unroll
            for (int mi2 = 0; mi2 < 2; mi2++) {
                const int row = wr * 128 + (p * 2 + mi2) * 16 + m;
#pragma unroll
                for (int kc = 0; kc < 2; kc++)
                    af[mi2][kc] = *(const bf16x8*)&Ac[(row * 8 + ((kc * 4 + g) ^ sw)) * 8];
            }
            if (p == 0) {
#pragma unroll
                for (int ni = 0; ni < NI; ni++) {
                    const int row = wc * (NI * 16) + ni * 16 + m;
#pragma unroll
                    for (int kc = 0; kc < 2; kc++)
                        bfv[ni][kc] = *(const bf16x8*)&Bc[(row * 8 + ((kc * 4 + g) ^ sw)) * 8];
                }
            }
            // front-loaded staging of tile t+1 (phases 0-1)
            if (pre) {
                if (p == 0) { stage_half(wrn, k1, 0); stage_half(wrn, k1, 1); }
                if (p == 1) { stage_half(wrn, k1, 2); if (NI == 4) stage_half(wrn, k1, 3); }
            }

            __builtin_amdgcn_s_barrier();
            asm volatile("s_waitcnt lgkmcnt(0)" ::: "memory");
            __builtin_amdgcn_s_setprio(1);
#pragma unroll
            for (int mi2 = 0; mi2 < 2; mi2++)
#pragma unroll
                for (int ni = 0; ni < NI; ni++)
#pragma unroll
                    for (int kc = 0; kc < 2; kc++)
                        acc[p * 2 + mi2][ni] = __builtin_amdgcn_mfma_f32_16x16x32_bf16(
                            af[mi2][kc], bfv[ni][kc], acc[p * 2 + mi2][ni], 0, 0, 0);
            __builtin_amdgcn_s_setprio(0);
            if (p == 3) {
                asm volatile("s_waitcnt vmcnt(0)" ::: "memory");
            }
            __builtin_amdgcn_s_barrier();
        }
    }

    // epilogue: C/D layout col=lane&15, row=g*4+reg
#pragma unroll
    for (int mi = 0; mi < 8; mi++) {
#pragma unroll
        for (int ni = 0; ni < NI; ni++) {
            const int col = bn + wc * (NI * 16) + ni * 16 + m;
            if (mode == 0) {
#pragma unroll
                for (int r = 0; r < 4; r++) {
                    const int row = bm + wr * 128 + mi * 16 + g * 4 + r;
                    C[(size_t)row * N + col] = acc[mi][ni][r];
                }
            } else {
                const int which = col >> 11;          // wave-uniform (64-col span)
                const int e = col & 2047;
                const int h = e >> 7;
                const int d = e & 127;
                if (which < 2) {
                    unsigned short* dst = (which == 0) ? qo : ko;
                    const int t2 = ((d >> 1) << 1);   // pair index *2
#pragma unroll
                    for (int r = 0; r < 4; r++) {
                        const int row = bm + wr * 128 + mi * 16 + g * 4 + r;
                        const int b = row >> 11;
                        const int l = row & 2047;
                        float val = acc[mi][ni][r];
                        const float prt = __shfl_xor(val, 1);
                        const float2 sc = *(const float2*)(rope + (size_t)l * HD + t2);
                        val = (m & 1) ? fmaf(val, sc.y, prt * sc.x)
                                      : fmaf(val, sc.y, -prt * sc.x);
                        dst[(((size_t)(b * NH + h)) * LSEQ + l) * HD + d] = f2bf(val);
                    }
                } else {
                    const int l0 = bm + wr * 128 + mi * 16 + g * 4;
                    const int b = l0 >> 11;
                    const int l = l0 & 2047;
                    ushort4 vv;
                    vv.x = f2bf(acc[mi][ni][0]);
                    vv.y = f2bf(acc[mi][ni][1]);
                    vv.z = f2bf(acc[mi][ni][2]);
                    vv.w = f2bf(acc[mi][ni][3]);
                    *(ushort4*)(vo + (((size_t)(b * NH + h)) * HD + d) * LSEQ + l) = vv;
                }
            }
        }
    }
}

// ---------------------------------------------------------------------------
// Proj GEMM engine — R2's 128x128 2-barrier kernel, verbatim (passed; 3
// blocks/CU at 32KB LDS, 512-block grid = full-GPU with cross-block overlap).
// C[m,n] = sum_k A[m,k]*B[n,k]; C fp32 row-major [M,N] (mode-0 path only).
// ---------------------------------------------------------------------------
__global__ __launch_bounds__(256) void gemm_bt_128(
    const unsigned short* __restrict__ A, const unsigned short* __restrict__ B,
    float* __restrict__ C, int M, int N, int K)
{
    __shared__ unsigned short As[128 * 64];  // 16 KB
    __shared__ unsigned short Bs[128 * 64];  // 16 KB

    const int tid = threadIdx.x;
    const int lane = tid & 63;
    const int w = tid >> 6;
    const int m = lane & 15;
    const int g = lane >> 4;
    const int wm = (w & 1) * 64;
    const int wn = (w >> 1) * 64;

    const int nwgx = gridDim.x;
    const int lin = blockIdx.y * nwgx + blockIdx.x;
    const int cpx = (nwgx * gridDim.y) >> 3;
    const int swz = (lin & 7) * cpx + (lin >> 3);
    const int bm = (swz / nwgx) * 128;
    const int bn = (swz % nwgx) * 128;

    f32x4 acc[4][4];
#pragma unroll
    for (int mi = 0; mi < 4; mi++)
#pragma unroll
        for (int ni = 0; ni < 4; ni++) acc[mi][ni] = (f32x4){0.f, 0.f, 0.f, 0.f};

    for (int k0 = 0; k0 < K; k0 += 64) {
        __syncthreads();
#pragma unroll
        for (int i = 0; i < 4; i++) {
            const int idx = i * 256 + tid;          // lane-linear LDS 16B slot
            const int row = idx >> 3;               // 0..127
            const int c = (idx & 7) ^ (row & 7);    // swizzled source chunk
            load_lds16(A + (size_t)(bm + row) * K + k0 + c * 8, &As[idx * 8]);
            load_lds16(B + (size_t)(bn + row) * K + k0 + c * 8, &Bs[idx * 8]);
        }
        __syncthreads();

#pragma unroll
        for (int kc = 0; kc < 2; kc++) {
            bf16x8 af[4], bfv[4];
#pragma unroll
            for (int mi = 0; mi < 4; mi++) {
                const int row = wm + mi * 16 + m;
                af[mi] = *(const bf16x8*)&As[(row * 8 + ((kc * 4 + g) ^ (m & 7))) * 8];
            }
#pragma unroll
            for (int ni = 0; ni < 4; ni++) {
                const int row = wn + ni * 16 + m;
                bfv[ni] = *(const bf16x8*)&Bs[(row * 8 + ((kc * 4 + g) ^ (m & 7))) * 8];
            }
#pragma unroll
            for (int mi = 0; mi < 4; mi++)
#pragma unroll
                for (int ni = 0; ni < 4; ni++)
                    acc[mi][ni] = __builtin_amdgcn_mfma_f32_16x16x32_bf16(
                        af[mi], bfv[ni], acc[mi][ni], 0, 0, 0);
        }
    }

    // epilogue: C/D layout col=lane&15, row=g*4+reg
#pragma unroll
    for (int mi = 0; mi < 4; mi++) {
#pragma unroll
        for (int ni = 0; ni < 4; ni++) {
            const int col = bn + wn + ni * 16 + m;
#pragma unroll
            for (int r = 0; r < 4; r++) {
                const int row = bm + wm + mi * 16 + g * 4 + r;
                C[(size_t)row * N + col] = acc[mi][ni][r];
            }
        }
    }
}

// ---------------------------------------------------------------------------
// MFMA bf16 flash attention (causal), double-buffered K/V pipeline.
// (R2 verbatim — verified passing repeatedly)
// ---------------------------------------------------------------------------
#define PTILES 32     // LSEQ / 64
#define PS_STR 68

__global__ __launch_bounds__(256) void attn_kernel(
    const unsigned short* __restrict__ q, const unsigned short* __restrict__ k,
    const unsigned short* __restrict__ vT, unsigned short* __restrict__ y)
{
    __shared__ __align__(16) unsigned short Ks[2][64 * 128];  // 2x16 KB [key][d] swizzled
    __shared__ __align__(16) unsigned short Vs[2][64 * 128];  // 2x16 KB [d][key] swizzled
    __shared__ __align__(16) unsigned short Ps[64 * PS_STR];  // 8704 B

    const int tid = threadIdx.x;
    const int lane = tid & 63;
    const int w = tid >> 6;
    const int m = lane & 15;
    const int g = lane >> 4;
    const int bh = blockIdx.x;                 // 0..31 (B*H)
    const int qt = PTILES - 1 - blockIdx.y;    // heavy tiles dispatched first
    const int q0 = qt * 64;
    const size_t base = (size_t)bh * LSEQ * HD;   // also [bh][HD][LSEQ] base for vT
    const float scale = 0.08838834764831845f;  // 1/sqrt(128)
    const int bB = bh / NH;
    const int hh = bh % NH;
    const int sw = m & 7;   // read-side swizzle key

    // stage K+V tile (swizzled source chunks, lane-linear LDS dest)
    auto stage = [&](int buf, int kb0) {
        const unsigned short* ksrc = k + base + (size_t)kb0 * HD;
#pragma unroll
        for (int i = 0; i < 4; i++) {
            const int idx = i * 256 + tid;
            const int row = idx >> 4;                 // 0..63
            const int c = (idx & 15) ^ (row & 7);     // source chunk
            load_lds16(ksrc + (size_t)row * HD + c * 8, &Ks[buf][idx * 8]);
        }
#pragma unroll
        for (int i = 0; i < 4; i++) {
            const int idx = i * 256 + tid;
            const int d = idx >> 3;                   // 0..127
            const int c = (idx & 7) ^ (d & 7);
            load_lds16(vT + base + (size_t)d * LSEQ + kb0 + c * 8, &Vs[buf][idx * 8]);
        }
    };

    // ---- Q fragments in registers (row = q0 + w*16 + m) ----
    bf16x8 aq[4];
    {
        const unsigned short* qrow = q + base + (size_t)(q0 + w * 16 + m) * HD;
#pragma unroll
        for (int kc = 0; kc < 4; kc++)
            aq[kc] = *(const bf16x8*)(qrow + kc * 32 + g * 8);
    }

    f32x4 o[8];
#pragma unroll
    for (int i = 0; i < 8; i++) o[i] = (f32x4){0.f, 0.f, 0.f, 0.f};
    float mprev[4], lsum[4];
#pragma unroll
    for (int r = 0; r < 4; r++) { mprev[r] = -1e30f; lsum[r] = 0.f; }

    // prologue: stage tile 0 into buffer 0
    stage(0, 0);
    int cur = 0;

    for (int kt = 0; kt <= qt; kt++) {
        const int k0 = kt * 64;

        // drains prefetch of buf[cur] (vmcnt(0) emitted before barrier) and
        // orders prior-iteration LDS reads before this iteration's staging
        __syncthreads();

        // issue next-tile prefetch now; it stays in flight through compute
        if (kt < qt) stage(cur ^ 1, k0 + 64);

        const unsigned short* Kc = Ks[cur];
        const unsigned short* Vc = Vs[cur];

        // ---- S = Q K^T (16 rows x 64 keys per wave) ----
        f32x4 s[4];
#pragma unroll
        for (int n = 0; n < 4; n++) {
            f32x4 acc = (f32x4){0.f, 0.f, 0.f, 0.f};
#pragma unroll
            for (int kc = 0; kc < 4; kc++) {
                const int row = n * 16 + m;
                bf16x8 bk = *(const bf16x8*)&Kc[(row * 16 + ((kc * 4 + g) ^ sw)) * 8];
                acc = __builtin_amdgcn_mfma_f32_16x16x32_bf16(aq[kc], bk, acc, 0, 0, 0);
            }
            s[n] = acc;
        }

        // ---- scale + causal mask (only the diagonal tile) ----
        const int rowg = q0 + w * 16 + g * 4;
        if (kt == qt) {
#pragma unroll
            for (int n = 0; n < 4; n++) {
                const int col = k0 + n * 16 + m;
#pragma unroll
                for (int r = 0; r < 4; r++) {
                    const float val = s[n][r] * scale;
                    s[n][r] = (col <= rowg + r) ? val : -1e30f;
                }
            }
        } else {
#pragma unroll
            for (int n = 0; n < 4; n++)
#pragma unroll
                for (int r = 0; r < 4; r++) s[n][r] *= scale;
        }

        // ---- online softmax ----
        float al[4];
#pragma unroll
        for (int r = 0; r < 4; r++) {
            float v0 = fmaxf(fmaxf(s[0][r], s[1][r]), fmaxf(s[2][r], s[3][r]));
            v0 = fmaxf(v0, __shfl_xor(v0, 1));
            v0 = fmaxf(v0, __shfl_xor(v0, 2));
            v0 = fmaxf(v0, __shfl_xor(v0, 4));
            v0 = fmaxf(v0, __shfl_xor(v0, 8));
            const float mn = fmaxf(mprev[r], v0);
            al[r] = __expf(mprev[r] - mn);
            mprev[r] = mn;
        }
#pragma unroll
        for (int r = 0; r < 4; r++) {
            float sum = 0.f;
#pragma unroll
            for (int n = 0; n < 4; n++) {
                const float p = __expf(s[n][r] - mprev[r]);
                sum += p;
                Ps[(w * 16 + g * 4 + r) * PS_STR + n * 16 + m] = f2bf(p);
            }
            sum += __shfl_xor(sum, 1);
            sum += __shfl_xor(sum, 2);
            sum += __shfl_xor(sum, 4);
            sum += __shfl_xor(sum, 8);
            lsum[r] = lsum[r] * al[r] + sum;
        }

        // ---- O = O*alpha + P V ----
#pragma unroll
        for (int dc = 0; dc < 8; dc++)
#pragma unroll
            for (int r = 0; r < 4; r++) o[dc][r] *= al[r];

        // per-wave private Ps rows; same-wave DS ordering suffices (no barrier)
        bf16x8 ap[2];
#pragma unroll
        for (int kk = 0; kk < 2; kk++)
            ap[kk] = *(const bf16x8*)&Ps[(w * 16 + m) * PS_STR + kk * 32 + g * 8];
#pragma unroll
        for (int dc = 0; dc < 8; dc++) {
#pragma unroll
            for (int kk = 0; kk < 2; kk++) {
                const int row = dc * 16 + m;
                bf16x8 bv = *(const bf16x8*)&Vc[(row * 8 + ((kk * 4 + g) ^ sw)) * 8];
                o[dc] = __builtin_amdgcn_mfma_f32_16x16x32_bf16(ap[kk], bv, o[dc], 0, 0, 0);
            }
        }

        cur ^= 1;
    }

    // ---- epilogue: normalize, write y bf16 [B, L, H, HD] ----
#pragma unroll
    for (int r = 0; r < 4; r++) {
        const float inv = 1.f / lsum[r];
        const int lrow = q0 + w * 16 + g * 4 + r;
        unsigned short* dst = y + (((size_t)bB * LSEQ + lrow) * NH + hh) * HD;
#pragma unroll
        for (int dc = 0; dc < 8; dc++)
            dst[dc * 16 + m] = f2bf(o[dc][r] * inv);
    }
}

// ---------------------------------------------------------------------------
extern "C" void kernel_launch(void* const* d_in, const int* in_sizes, int n_in,
                              void* d_out, int out_size, void* d_ws, size_t ws_size,
                              hipStream_t stream) {
    const float* x      = (const float*)d_in[0];
    const float* rope   = (const float*)d_in[1];
    const float* w_attn = (const float*)d_in[2];
    const float* w_proj = (const float*)d_in[3];
    float* out = (float*)d_out;
    unsigned short* ws = (unsigned short*)d_ws;

    const size_t per = (size_t)BATCH * NH * LSEQ * HD;  // 8,388,608
    unsigned short* qb  = ws;
    unsigned short* kb  = ws + per;
    unsigned short* vb  = ws + 2 * per;   // transposed layout [B,H,HD,L]
    unsigned short* yb  = ws + 3 * per;
    unsigned short* xb  = ws + 4 * per;
    unsigned short* wab = xb + (size_t)N1;
    unsigned short* wpb = wab + (size_t)N2;

    const int M = BATCH * LSEQ;  // 4096

    // 0) cast inputs to bf16
    const int cast_blocks = (N1 + N2 + N3) / 4 / 256;
    cast_bf16_kernel<<<cast_blocks, 256, 0, stream>>>(x, w_attn, w_proj, xb, wab, wpb);

    // 1) QKV projection (R5 4-phase 256x256 engine, passed) + fused RoPE
    dim3 g1(3 * EMB / 256, M / 256);  // (24, 16) -> nwg 384 (%8==0)
    gemm_bt_bf16<4><<<g1, 512, 0, stream>>>(xb, wab, rope, nullptr, qb, kb, vb,
                                            M, 3 * EMB, EMB, 1);

    // 2) causal flash attention -> y bf16 (LPT grid: heavy q-tiles first)
    dim3 ga(BATCH * NH, PTILES);  // (32, 32)
    attn_kernel<<<ga, 256, 0, stream>>>(qb, kb, vb, yb);

    // 3) output projection (R2 128x128 engine, 512 blocks, 3 blocks/CU, passed)
    dim3 g2(EMB / 128, M / 128);  // (16, 32) -> nwg 512 (%8==0)
    gemm_bt_128<<<g2, 256, 0, stream>>>(yb, wpb, out, M, EMB, EMB);
}